// Round 3
// baseline (11433.791 us; speedup 1.0000x reference)
//
#include <hip/hip_runtime.h>
#include <hip/hip_bf16.h>
#include <hip/hip_cooperative_groups.h>

namespace cg = cooperative_groups;

// N=128, T=128, D=1024, H=1024, 4H=4096.
// Serial GEMM K = 2048: act = [h | x], weights = [Wh | Wx] (reordered cols).
// Reordered col c = 4*unit + gate  <->  orig col j = gate*1024 + unit.
// attn@Wattn handled as rank-16 update with AW[n][c][p] = sum_u A[n,u,p]*Wattn[u,j(c)].
// scores s[n,p] = sum_u h[n,u]*A[n,u,p] accumulated as per-block partials sp[cs][n][p]
// inside the epilogue (h is in registers there).

typedef __bf16 bf16x8 __attribute__((ext_vector_type(8)));
typedef float f32x4 __attribute__((ext_vector_type(4)));

__device__ __forceinline__ unsigned short f2bf(float f) {
    unsigned int u = __float_as_uint(f);
    u += 0x7FFFu + ((u >> 16) & 1u);   // round-to-nearest-even
    return (unsigned short)(u >> 16);
}
__device__ __forceinline__ float bf2f(unsigned short u) {
    return __uint_as_float(((unsigned int)u) << 16);
}
__device__ __forceinline__ float sigf(float x) { return 1.0f / (1.0f + expf(-x)); }

// ---------------------------------------------------------------------------
// WTf: fragment-linear bf16 weight image, K=2048, [Wh | Wx].
// slot(s in [0,128), ks in [0,64), cf in {0,1}, l in [0,64)) holds 8 bf16:
//   col = s*32 + cf*16 + (l&15), k = ks*32 + (l>>4)*8 + i.
// Built via LDS tile for coalesced W reads.
// ---------------------------------------------------------------------------
__global__ __launch_bounds__(256) void k_build_wtf2(
    const float* __restrict__ Wh, const float* __restrict__ Wx,
    unsigned short* __restrict__ WTf) {
    __shared__ float tile[64][65];
    const int cs2 = blockIdx.x;   // 64: cols [cs2*64, +64)
    const int kq  = blockIdx.y;   // 32: k [kq*64, +64)
    const int tid = threadIdx.x;
#pragma unroll
    for (int it = 0; it < 16; ++it) {
        int idx = it * 256 + tid;
        int kl = idx >> 6, cl = idx & 63;
        int col = cs2 * 64 + cl;
        int j = (col & 3) * 1024 + (col >> 2);
        int k = kq * 64 + kl;
        tile[kl][cl] = (k < 1024) ? Wh[(size_t)k * 4096 + j]
                                  : Wx[(size_t)(k - 1024) * 4096 + j];
    }
    __syncthreads();
#pragma unroll
    for (int it = 0; it < 2; ++it) {
        int slotid = it * 256 + tid;        // 512 slots
        int l   = slotid & 63;
        int cf  = (slotid >> 6) & 1;
        int ksl = (slotid >> 7) & 1;
        int sl  = slotid >> 8;
        int s = cs2 * 2 + sl, ks = kq * 2 + ksl;
        int clocal = sl * 32 + cf * 16 + (l & 15);
        int klocal = ksl * 32 + ((l >> 4) << 3);
        unsigned short v[8];
#pragma unroll
        for (int i = 0; i < 8; ++i) v[i] = f2bf(tile[klocal + i][clocal]);
        *(int4*)&WTf[(size_t)(((s * 64 + ks) * 2 + cf) * 64 + l) * 8] = *(const int4*)v;
    }
}

// ---------------------------------------------------------------------------
// AW[n][c][p] (bf16) = sum_u A[n,u,p] * Wattn[u, j(c)].  f32 accumulate.
// grid (32 jt x 8 ng); block loops 16 n with A[n] staged in 64KB dyn-LDS.
// ---------------------------------------------------------------------------
__global__ __launch_bounds__(512) void k_build_aw(
    const float* __restrict__ Wattn, const float* __restrict__ Ag,
    unsigned short* __restrict__ AW) {
    extern __shared__ float Alds[];   // [1024][16] f32 = 64KB
    const int jt = blockIdx.x;        // 32: j [jt*128, +128)
    const int ng = blockIdx.y;        // 8: n [ng*16, +16)
    const int tid = threadIdx.x;
    const int jl = tid & 127, pg = tid >> 7;   // pg in [0,4)
    const int jj = jt * 128 + jl;
    for (int nn = 0; nn < 16; ++nn) {
        const int n = ng * 16 + nn;
        __syncthreads();
#pragma unroll
        for (int q = 0; q < 8; ++q) {
            int idx = q * 512 + tid;  // 4096 float4
            ((float4*)Alds)[idx] = ((const float4*)(Ag + (size_t)n * 16384))[idx];
        }
        __syncthreads();
        f32x4 acc = {0.f, 0.f, 0.f, 0.f};
#pragma unroll 8
        for (int u = 0; u < 1024; ++u) {
            float wv = Wattn[(size_t)u * 4096 + jj];
            const float4 av = *(const float4*)&Alds[u * 16 + pg * 4];
            acc[0] += wv * av.x; acc[1] += wv * av.y;
            acc[2] += wv * av.z; acc[3] += wv * av.w;
        }
        const int g = jj >> 10, unit = jj & 1023;
        const int cre = unit * 4 + g;
        ushort4 st = make_ushort4(f2bf(acc[0]), f2bf(acc[1]), f2bf(acc[2]), f2bf(acc[3]));
        *(ushort4*)&AW[((size_t)n * 4096 + cre) * 16 + pg * 4] = st;
    }
}

// ---------------------------------------------------------------------------
// h0 = c0 = mean over 16 positions of A; writes c, actF0 h-part (frag layout),
// and initial score partials sp[cs][n][p].
// ---------------------------------------------------------------------------
__global__ __launch_bounds__(512) void k_init(
    const float* __restrict__ Ag, float* __restrict__ cst,
    unsigned short* __restrict__ actF0, float* __restrict__ sp) {
    const int n = blockIdx.x;
    const int t = threadIdx.x;
    float contrib[16];
#pragma unroll
    for (int p = 0; p < 16; ++p) contrib[p] = 0.f;
#pragma unroll
    for (int e = 0; e < 2; ++e) {
        const int u = t * 2 + e;
        const float4* ap = (const float4*)&Ag[((size_t)n * 1024 + u) * 16];
        float4 a0 = ap[0], a1 = ap[1], a2 = ap[2], a3 = ap[3];
        float s = a0.x + a0.y + a0.z + a0.w + a1.x + a1.y + a1.z + a1.w +
                  a2.x + a2.y + a2.z + a2.w + a3.x + a3.y + a3.z + a3.w;
        float h0 = s * (1.0f / 16.0f);
        cst[n * 1024 + u] = h0;
        const int rfg = n >> 4, kc = u >> 5, l = (n & 15) | (((u >> 3) & 3) << 4);
        actF0[(size_t)((rfg * 64 + kc) * 64 + l) * 8 + (u & 7)] = f2bf(h0);
        contrib[0]  += h0 * a0.x;  contrib[1]  += h0 * a0.y;
        contrib[2]  += h0 * a0.z;  contrib[3]  += h0 * a0.w;
        contrib[4]  += h0 * a1.x;  contrib[5]  += h0 * a1.y;
        contrib[6]  += h0 * a1.z;  contrib[7]  += h0 * a1.w;
        contrib[8]  += h0 * a2.x;  contrib[9]  += h0 * a2.y;
        contrib[10] += h0 * a2.z;  contrib[11] += h0 * a2.w;
        contrib[12] += h0 * a3.x;  contrib[13] += h0 * a3.y;
        contrib[14] += h0 * a3.z;  contrib[15] += h0 * a3.w;
    }
#pragma unroll
    for (int p = 0; p < 16; ++p) {
        contrib[p] += __shfl_xor(contrib[p], 1);
        contrib[p] += __shfl_xor(contrib[p], 2);
    }
    if ((t & 3) == 0) {
        const int cs = t >> 2;   // u-range [cs*8, +8)
        float4* dst = (float4*)&sp[((size_t)cs * 128 + n) * 16];
        dst[0] = make_float4(contrib[0], contrib[1], contrib[2], contrib[3]);
        dst[1] = make_float4(contrib[4], contrib[5], contrib[6], contrib[7]);
        dst[2] = make_float4(contrib[8], contrib[9], contrib[10], contrib[11]);
        dst[3] = make_float4(contrib[12], contrib[13], contrib[14], contrib[15]);
    }
}

// ---------------------------------------------------------------------------
// Persistent cooperative kernel: 256 blocks x 512 threads, 1 block/CU.
// Block b: rh = b&1 (row half, 64 rows), cs = b>>1 (32 reordered cols).
// LDS: Wlds 128KB (whole K=2048 weight slice, loaded once) + scratch.
// Per step: P1 (scores reduce+softmax | x-pack) -> grid.sync ->
//           P2 (MFMA gemm, K-split over 2 wave-groups, LDS partial reduce,
//               fused epilogue: bias + rank-16 attn + gates + state update +
//               sp partials for next step's scores) -> grid.sync.
// ---------------------------------------------------------------------------
__global__ __launch_bounds__(512, 2) void k_persist(
    const unsigned short* __restrict__ WTf, const unsigned short* __restrict__ AW,
    unsigned short* __restrict__ actF0, unsigned short* __restrict__ actF1,
    float* __restrict__ sp, float* __restrict__ w_ws, float* __restrict__ cst,
    const float* __restrict__ Ag, const float* __restrict__ x,
    const float* __restrict__ bptr, float* __restrict__ out) {
    extern __shared__ char smem[];
    unsigned short* Wlds = (unsigned short*)smem;          // 131072 B
    float* sc_lds = (float*)(smem + 131072);               // 64 B (+pad)
    float* accred = (float*)(smem + 131072 + 256);         // 8192 B

    const int bid = blockIdx.x;
    const int rh = bid & 1, cs = bid >> 1;
    const int tid = threadIdx.x;
    const int lane = tid & 63, wave = tid >> 6;

    // one-time: load this block's full weight slice (128 KB) into LDS
    {
        const int4* src = (const int4*)(WTf + (size_t)cs * 65536);
        int4* dst = (int4*)Wlds;
#pragma unroll
        for (int i = 0; i < 16; ++i) dst[i * 512 + tid] = src[i * 512 + tid];
    }
    __syncthreads();

    cg::grid_group grid = cg::this_grid();

    for (int ts = 0; ts < 128; ++ts) {
        unsigned short* actT  = (ts & 1) ? actF1 : actF0;
        unsigned short* actT2 = (ts & 1) ? actF0 : actF1;

        // ---------------- P1 ----------------
        if (!(bid & 1)) {
            // scores for n = bid>>1: reduce sp over 128 col-slices, softmax -> w_ws
            const int n = bid >> 1;
            const int p = tid >> 5, csq = tid & 31;
            float part = 0.f;
#pragma unroll
            for (int q = 0; q < 4; ++q)
                part += sp[(size_t)((csq * 4 + q) * 128 + n) * 16 + p];
#pragma unroll
            for (int off = 1; off <= 16; off <<= 1) part += __shfl_xor(part, off);
            if (csq == 0) sc_lds[p] = part;
            __syncthreads();
            if (tid == 0) {
                float sc[16], mx = -1e30f, se = 0.f;
#pragma unroll
                for (int q = 0; q < 16; ++q) { sc[q] = sc_lds[q] * 0.03125f; mx = fmaxf(mx, sc[q]); }
#pragma unroll
                for (int q = 0; q < 16; ++q) { sc[q] = expf(sc[q] - mx); se += sc[q]; }
                const float inv = 1.f / se;
#pragma unroll
                for (int q = 0; q < 16; ++q) w_ws[n * 16 + q] = sc[q] * inv;
            }
        } else {
            // x-pack for n = bid>>1 into frag-linear act (k = 1024 + j)
            const int n = bid >> 1;
            if (tid < 128) {
                const int j0 = tid * 8;
                const float4* xp = (const float4*)&x[((size_t)n * 128 + ts) * 1024 + j0];
                float4 x0 = xp[0], x1 = xp[1];
                unsigned short v[8] = {f2bf(x0.x), f2bf(x0.y), f2bf(x0.z), f2bf(x0.w),
                                       f2bf(x1.x), f2bf(x1.y), f2bf(x1.z), f2bf(x1.w)};
                const int k = 1024 + j0;
                const int rfg = n >> 4, kc = k >> 5, l = (n & 15) | (((k >> 3) & 3) << 4);
                *(int4*)&actT[(size_t)((rfg * 64 + kc) * 64 + l) * 8] = *(const int4*)v;
            }
        }
        grid.sync();

        // ---------------- P2 ----------------
        {
            const int rf = wave & 3, kh = wave >> 2;
            const int rfg = rh * 4 + rf;
            f32x4 acc0 = {0.f, 0.f, 0.f, 0.f}, acc1 = {0.f, 0.f, 0.f, 0.f};
            const int kc0 = kh * 32;
#pragma unroll 4
            for (int kc = kc0; kc < kc0 + 32; ++kc) {
                bf16x8 af = *(const bf16x8*)&actT[(size_t)((rfg * 64 + kc) * 64 + lane) * 8];
                bf16x8 b0 = *(const bf16x8*)&Wlds[((kc * 2 + 0) * 64 + lane) * 8];
                bf16x8 b1 = *(const bf16x8*)&Wlds[((kc * 2 + 1) * 64 + lane) * 8];
                acc0 = __builtin_amdgcn_mfma_f32_16x16x32_bf16(af, b0, acc0, 0, 0, 0);
                acc1 = __builtin_amdgcn_mfma_f32_16x16x32_bf16(af, b1, acc1, 0, 0, 0);
            }
            if (kh == 1) {
                *(f32x4*)&accred[((rf * 2 + 0) * 64 + lane) * 4] = acc0;
                *(f32x4*)&accred[((rf * 2 + 1) * 64 + lane) * 4] = acc1;
            }
            __syncthreads();
            if (kh == 0) {
                acc0 += *(const f32x4*)&accred[((rf * 2 + 0) * 64 + lane) * 4];
                acc1 += *(const f32x4*)&accred[((rf * 2 + 1) * 64 + lane) * 4];
                const int lq = lane & 15;
                float nhv[2][4];
                int uu[2];
                f32x4 accs[2] = {acc0, acc1};
#pragma unroll
                for (int cf = 0; cf < 2; ++cf) {
                    const int col = cs * 32 + cf * 16 + lq;
                    const int u = col >> 2, g = col & 3;
                    uu[cf] = u;
                    const float bias = bptr[g * 1024 + u];
#pragma unroll
                    for (int reg = 0; reg < 4; ++reg) {
                        const int r = rh * 64 + rf * 16 + ((lane >> 4) << 2) + reg;
                        // rank-16 attention term
                        const float* wp = &w_ws[r * 16];
                        const unsigned short* awp = &AW[((size_t)r * 4096 + col) * 16];
                        float aextra = 0.f;
#pragma unroll
                        for (int p = 0; p < 16; ++p) aextra += wp[p] * bf2f(awp[p]);
                        float a = accs[cf][reg] + bias + aextra;
                        float v1 = __shfl_xor(a, 1);
                        float v2 = __shfl_xor(a, 2);
                        float v3 = __shfl_xor(a, 3);
                        auto pick = [&](int m) { return m == 0 ? a : m == 1 ? v1 : m == 2 ? v2 : v3; };
                        float ii = sigf(pick(g));
                        float ff = sigf(pick(g ^ 1));
                        float oo = sigf(pick(g ^ 2));
                        float gg = tanhf(pick(g ^ 3));
                        const float cold = cst[r * 1024 + u];
                        const float nc = ff * cold + ii * gg;
                        const float nh = oo * tanhf(nc);
                        nhv[cf][reg] = nh;
                        if (g == 0) {
                            cst[r * 1024 + u] = nc;
                        } else if (g == 1) {
                            const int rfg2 = r >> 4, kc2 = u >> 5,
                                      l2 = (r & 15) | (((u >> 3) & 3) << 4);
                            actT2[(size_t)((rfg2 * 64 + kc2) * 64 + l2) * 8 + (u & 7)] = f2bf(nh);
                        } else if (g == 3) {
                            out[((size_t)r * 128 + ts) * 1024 + u] = nh;
                        }
                    }
                }
                // sp partials for next step's scores (g==2 lanes only; lane&3==2
                // so all shfl_xor(4/8) partners are active)
                if ((lane & 3) == 2) {
#pragma unroll
                    for (int reg = 0; reg < 4; ++reg) {
                        const int r = rh * 64 + rf * 16 + ((lane >> 4) << 2) + reg;
                        const float n0 = nhv[0][reg], n1 = nhv[1][reg];
                        const float4* A0 = (const float4*)&Ag[((size_t)r * 1024 + uu[0]) * 16];
                        const float4* A1 = (const float4*)&Ag[((size_t)r * 1024 + uu[1]) * 16];
                        float contrib[16];
#pragma unroll
                        for (int q = 0; q < 4; ++q) {
                            float4 c0 = A0[q], c1 = A1[q];
                            contrib[q * 4 + 0] = n0 * c0.x + n1 * c1.x;
                            contrib[q * 4 + 1] = n0 * c0.y + n1 * c1.y;
                            contrib[q * 4 + 2] = n0 * c0.z + n1 * c1.z;
                            contrib[q * 4 + 3] = n0 * c0.w + n1 * c1.w;
                        }
#pragma unroll
                        for (int p = 0; p < 16; ++p) {
                            contrib[p] += __shfl_xor(contrib[p], 4);
                            contrib[p] += __shfl_xor(contrib[p], 8);
                        }
                        if (lq == 2) {
                            float4* dst = (float4*)&sp[((size_t)cs * 128 + r) * 16];
                            dst[0] = make_float4(contrib[0], contrib[1], contrib[2], contrib[3]);
                            dst[1] = make_float4(contrib[4], contrib[5], contrib[6], contrib[7]);
                            dst[2] = make_float4(contrib[8], contrib[9], contrib[10], contrib[11]);
                            dst[3] = make_float4(contrib[12], contrib[13], contrib[14], contrib[15]);
                        }
                    }
                }
            }
        }
        grid.sync();
    }
}

extern "C" void kernel_launch(void* const* d_in, const int* in_sizes, int n_in,
                              void* d_out, int out_size, void* d_ws, size_t ws_size,
                              hipStream_t stream) {
    const float* x     = (const float*)d_in[0];   // (128,128,1024)
    const float* A     = (const float*)d_in[1];   // (128,1024,4,4)
    const float* Wx    = (const float*)d_in[2];   // (1024,4096)
    const float* Wh    = (const float*)d_in[3];   // (1024,4096)
    const float* Wattn = (const float*)d_in[4];   // (1024,4096)
    const float* b     = (const float*)d_in[5];   // (4096,)
    float* out = (float*)d_out;                   // (128,128,1024) f32

    char* ws = (char*)d_ws;
    unsigned short* WTf   = (unsigned short*)(ws);              // 16 MB
    unsigned short* AW    = (unsigned short*)(ws + 16777216);   // 16 MB
    unsigned short* actF0 = (unsigned short*)(ws + 33554432);   // 512 KB
    unsigned short* actF1 = (unsigned short*)(ws + 34078720);   // 512 KB
    float* sp   = (float*)(ws + 34603008);                      // 1 MB
    float* w_ws = (float*)(ws + 35651584);                      // 8 KB
    float* cst  = (float*)(ws + 35659776);                      // 512 KB

    k_build_wtf2<<<dim3(64, 32), 256, 0, stream>>>(Wh, Wx, WTf);
    k_build_aw<<<dim3(32, 8), 512, 65536, stream>>>(Wattn, A, AW);
    k_init<<<128, 512, 0, stream>>>(A, cst, actF0, sp);

    const unsigned short* WTfc = WTf;
    const unsigned short* AWc  = AW;
    unsigned short* a0p = actF0;
    unsigned short* a1p = actF1;
    float* spp = sp;
    float* wwp = w_ws;
    float* cp  = cst;
    const float* Ap = A;
    const float* xp = x;
    const float* bp = b;
    float* op = out;
    void* args[11];
    args[0]  = (void*)&WTfc;
    args[1]  = (void*)&AWc;
    args[2]  = (void*)&a0p;
    args[3]  = (void*)&a1p;
    args[4]  = (void*)&spp;
    args[5]  = (void*)&wwp;
    args[6]  = (void*)&cp;
    args[7]  = (void*)&Ap;
    args[8]  = (void*)&xp;
    args[9]  = (void*)&bp;
    args[10] = (void*)&op;
    hipLaunchCooperativeKernel((const void*)k_persist, dim3(256), dim3(512),
                               args, 139520, stream);
}

// Round 4
// 4359.248 us; speedup vs baseline: 2.6229x; 2.6229x over previous
//
#include <hip/hip_runtime.h>
#include <hip/hip_bf16.h>

// N=128, T=128, D=1024, H=1024, 4H=4096.
// Serial GEMM K = 2048: act = [h | x], weights = [Wh | Wx] (reordered cols).
// Reordered col c = 4*unit + gate  <->  orig col j = gate*1024 + unit.
// attn@Wattn = rank-16 update: AW[n][c][p] = sum_u A[n,u,p]*Wattn[u,j(c)].
// scores s[n,p] = sum_u h[n,u]*A[n,u,p]: per-block partials sp[cs][n][p] written
// by step t-1's epilogue, reduced in step t's prologue (fixed order).
// One kernel launch per step; launch boundary = global sync.

typedef __bf16 bf16x8 __attribute__((ext_vector_type(8)));
typedef float f32x4 __attribute__((ext_vector_type(4)));

__device__ __forceinline__ unsigned short f2bf(float f) {
    unsigned int u = __float_as_uint(f);
    u += 0x7FFFu + ((u >> 16) & 1u);   // round-to-nearest-even
    return (unsigned short)(u >> 16);
}
__device__ __forceinline__ float bf2f(unsigned short u) {
    return __uint_as_float(((unsigned int)u) << 16);
}
__device__ __forceinline__ float sigf(float x) { return 1.0f / (1.0f + expf(-x)); }

// ---------------------------------------------------------------------------
// WTf: fragment-linear bf16 weight image, K=2048, [Wh | Wx].
// slot(s in [0,128), ks in [0,64), cf in {0,1}, l in [0,64)) holds 8 bf16:
//   col = s*32 + cf*16 + (l&15), k = ks*32 + (l>>4)*8 + i.
// ---------------------------------------------------------------------------
__global__ __launch_bounds__(256) void k_build_wtf2(
    const float* __restrict__ Wh, const float* __restrict__ Wx,
    unsigned short* __restrict__ WTf) {
    __shared__ float tile[64][65];
    const int cs2 = blockIdx.x;   // 64: cols [cs2*64, +64)
    const int kq  = blockIdx.y;   // 32: k [kq*64, +64)
    const int tid = threadIdx.x;
#pragma unroll
    for (int it = 0; it < 16; ++it) {
        int idx = it * 256 + tid;
        int kl = idx >> 6, cl = idx & 63;
        int col = cs2 * 64 + cl;
        int j = (col & 3) * 1024 + (col >> 2);
        int k = kq * 64 + kl;
        tile[kl][cl] = (k < 1024) ? Wh[(size_t)k * 4096 + j]
                                  : Wx[(size_t)(k - 1024) * 4096 + j];
    }
    __syncthreads();
#pragma unroll
    for (int it = 0; it < 2; ++it) {
        int slotid = it * 256 + tid;        // 512 slots
        int l   = slotid & 63;
        int cf  = (slotid >> 6) & 1;
        int ksl = (slotid >> 7) & 1;
        int sl  = slotid >> 8;
        int s = cs2 * 2 + sl, ks = kq * 2 + ksl;
        int clocal = sl * 32 + cf * 16 + (l & 15);
        int klocal = ksl * 32 + ((l >> 4) << 3);
        unsigned short v[8];
#pragma unroll
        for (int i = 0; i < 8; ++i) v[i] = f2bf(tile[klocal + i][clocal]);
        *(int4*)&WTf[(size_t)(((s * 64 + ks) * 2 + cf) * 64 + l) * 8] = *(const int4*)v;
    }
}

// ---------------------------------------------------------------------------
// AW[n][c][p] (bf16) = sum_u A[n,u,p] * Wattn[u, j(c)].  f32 accumulate.
// ---------------------------------------------------------------------------
__global__ __launch_bounds__(512) void k_build_aw(
    const float* __restrict__ Wattn, const float* __restrict__ Ag,
    unsigned short* __restrict__ AW) {
    extern __shared__ float Alds[];   // [1024][16] f32 = 64KB
    const int jt = blockIdx.x;        // 32: j [jt*128, +128)
    const int ng = blockIdx.y;        // 8: n [ng*16, +16)
    const int tid = threadIdx.x;
    const int jl = tid & 127, pg = tid >> 7;   // pg in [0,4)
    const int jj = jt * 128 + jl;
    for (int nn = 0; nn < 16; ++nn) {
        const int n = ng * 16 + nn;
        __syncthreads();
#pragma unroll
        for (int q = 0; q < 8; ++q) {
            int idx = q * 512 + tid;  // 4096 float4
            ((float4*)Alds)[idx] = ((const float4*)(Ag + (size_t)n * 16384))[idx];
        }
        __syncthreads();
        f32x4 acc = {0.f, 0.f, 0.f, 0.f};
#pragma unroll 8
        for (int u = 0; u < 1024; ++u) {
            float wv = Wattn[(size_t)u * 4096 + jj];
            const float4 av = *(const float4*)&Alds[u * 16 + pg * 4];
            acc[0] += wv * av.x; acc[1] += wv * av.y;
            acc[2] += wv * av.z; acc[3] += wv * av.w;
        }
        const int g = jj >> 10, unit = jj & 1023;
        const int cre = unit * 4 + g;
        ushort4 st = make_ushort4(f2bf(acc[0]), f2bf(acc[1]), f2bf(acc[2]), f2bf(acc[3]));
        *(ushort4*)&AW[((size_t)n * 4096 + cre) * 16 + pg * 4] = st;
    }
}

// ---------------------------------------------------------------------------
// h0 = c0 = mean over 16 positions of A. Writes cst, hF0 (frag layout,
// K-h part only: 32 kc), xf0 (x[:,0] frag-packed), sp0 partials.
// One block per n, 512 threads.
// ---------------------------------------------------------------------------
__global__ __launch_bounds__(512) void k_init(
    const float* __restrict__ Ag, const float* __restrict__ x,
    float* __restrict__ cst, unsigned short* __restrict__ hF0,
    unsigned short* __restrict__ xf0, float* __restrict__ sp) {
    const int n = blockIdx.x;
    const int t = threadIdx.x;
    // pack x[:, t=0]
    if (t < 128) {
        const int j0 = t * 8;
        const float4* xp = (const float4*)&x[((size_t)n * 128 + 0) * 1024 + j0];
        float4 x0 = xp[0], x1 = xp[1];
        unsigned short v[8] = {f2bf(x0.x), f2bf(x0.y), f2bf(x0.z), f2bf(x0.w),
                               f2bf(x1.x), f2bf(x1.y), f2bf(x1.z), f2bf(x1.w)};
        const int rfg = n >> 4, kc = j0 >> 5, l = (n & 15) | (((j0 >> 3) & 3) << 4);
        *(int4*)&xf0[(size_t)((rfg * 32 + kc) * 64 + l) * 8] = *(const int4*)v;
    }
    float contrib[16];
#pragma unroll
    for (int p = 0; p < 16; ++p) contrib[p] = 0.f;
#pragma unroll
    for (int e = 0; e < 2; ++e) {
        const int u = t * 2 + e;
        const float4* ap = (const float4*)&Ag[((size_t)n * 1024 + u) * 16];
        float4 a0 = ap[0], a1 = ap[1], a2 = ap[2], a3 = ap[3];
        float s = a0.x + a0.y + a0.z + a0.w + a1.x + a1.y + a1.z + a1.w +
                  a2.x + a2.y + a2.z + a2.w + a3.x + a3.y + a3.z + a3.w;
        float h0 = s * (1.0f / 16.0f);
        cst[n * 1024 + u] = h0;
        const int rfg = n >> 4, kc = u >> 5, l = (n & 15) | (((u >> 3) & 3) << 4);
        hF0[(size_t)((rfg * 32 + kc) * 64 + l) * 8 + (u & 7)] = f2bf(h0);
        contrib[0]  += h0 * a0.x;  contrib[1]  += h0 * a0.y;
        contrib[2]  += h0 * a0.z;  contrib[3]  += h0 * a0.w;
        contrib[4]  += h0 * a1.x;  contrib[5]  += h0 * a1.y;
        contrib[6]  += h0 * a1.z;  contrib[7]  += h0 * a1.w;
        contrib[8]  += h0 * a2.x;  contrib[9]  += h0 * a2.y;
        contrib[10] += h0 * a2.z;  contrib[11] += h0 * a2.w;
        contrib[12] += h0 * a3.x;  contrib[13] += h0 * a3.y;
        contrib[14] += h0 * a3.z;  contrib[15] += h0 * a3.w;
    }
#pragma unroll
    for (int p = 0; p < 16; ++p) {
        contrib[p] += __shfl_xor(contrib[p], 1);
        contrib[p] += __shfl_xor(contrib[p], 2);
    }
    if ((t & 3) == 0) {
        const int cs = t >> 2;   // unit range [cs*8, +8)
        float4* dst = (float4*)&sp[((size_t)cs * 128 + n) * 16];
        dst[0] = make_float4(contrib[0], contrib[1], contrib[2], contrib[3]);
        dst[1] = make_float4(contrib[4], contrib[5], contrib[6], contrib[7]);
        dst[2] = make_float4(contrib[8], contrib[9], contrib[10], contrib[11]);
        dst[3] = make_float4(contrib[12], contrib[13], contrib[14], contrib[15]);
    }
}

// ---------------------------------------------------------------------------
// One time step. 256 blocks x 512 threads. Block (cs = bid>>1, rh = bid&1):
// 64 rows x 32 reordered cols, K=2048 split over kh wave-halves.
// Prologue: reduce sp partials -> softmax weights (LDS).
// GEMM: frag-linear A (hF / xf) and B (WTf) direct from global, no barriers.
// One barrier: cross-kh accumulate via LDS. Epilogue (kh==0 waves): bias +
// rank-16 attn + gates + state update + out + next-step sp partials.
// kh==1 waves pack x for step ts+1 after the barrier.
// ---------------------------------------------------------------------------
__global__ __launch_bounds__(512) void k_step(
    const unsigned short* __restrict__ WTf, const unsigned short* __restrict__ AW,
    const unsigned short* __restrict__ hFin, unsigned short* __restrict__ hFout,
    const unsigned short* __restrict__ xfin, unsigned short* __restrict__ xfout,
    const float* __restrict__ spin, float* __restrict__ spout,
    float* __restrict__ cst, const float* __restrict__ Ag,
    const float* __restrict__ x, const float* __restrict__ bias4,
    float* __restrict__ out, int ts) {
    __shared__ float psum[2][64][16];     // 8 KB
    __shared__ float wlds[64][17];        // 4.25 KB (pad vs 4-row stride)
    __shared__ float accred[2048];        // 8 KB
    const int bid = blockIdx.x;
    const int cs = bid >> 1, rh = bid & 1;
    const int tid = threadIdx.x;
    const int lane = tid & 63, wave = tid >> 6;

    // ---- prologue phase A: partial sp reduce (each thread: 64 cs-slices) ----
    {
        const int pq = tid & 3, nl = (tid >> 2) & 63, half = tid >> 8;
        const int n = rh * 64 + nl;
        f32x4 ps = {0.f, 0.f, 0.f, 0.f};
        const float* base = &spin[(size_t)((half * 64) * 128 + n) * 16 + pq * 4];
#pragma unroll 8
        for (int c2 = 0; c2 < 64; ++c2) {
            const float4 v = *(const float4*)(base + (size_t)c2 * 2048);
            ps[0] += v.x; ps[1] += v.y; ps[2] += v.z; ps[3] += v.w;
        }
        *(f32x4*)&psum[half][nl][pq * 4] = ps;
    }
    __syncthreads();
    // ---- prologue phase B: combine halves + softmax -> wlds ----
    {
#pragma unroll
        for (int it = 0; it < 2; ++it) {
            const int idx = it * 512 + tid;     // 1024 = 64 nl x 16 p
            const int nl = idx >> 4, p = idx & 15;
            float s = psum[0][nl][p] + psum[1][nl][p];
            float mx = s;
#pragma unroll
            for (int m = 1; m < 16; m <<= 1) mx = fmaxf(mx, __shfl_xor(mx, m));
            float e = expf((s - mx) * 0.03125f);
            float se = e;
#pragma unroll
            for (int m = 1; m < 16; m <<= 1) se += __shfl_xor(se, m);
            wlds[nl][p] = e / se;
        }
    }

    // ---- GEMM (no barrier inside) ----
    const int rf = wave & 3, kh = wave >> 2;
    const int rfg = rh * 4 + rf;
    f32x4 acc0 = {0.f, 0.f, 0.f, 0.f}, acc1 = {0.f, 0.f, 0.f, 0.f};
    {
        const unsigned short* aptr = (kh == 0)
            ? hFin + (size_t)rfg * 32 * 512 + lane * 8
            : xfin + (size_t)rfg * 32 * 512 + lane * 8;
        const unsigned short* bp = WTf + (size_t)(cs * 64 + kh * 32) * 2 * 512 + lane * 8;
#pragma unroll 4
        for (int kc = 0; kc < 32; ++kc) {
            bf16x8 af = *(const bf16x8*)(aptr + (size_t)kc * 512);
            bf16x8 b0 = *(const bf16x8*)(bp + (size_t)(kc * 2) * 512);
            bf16x8 b1 = *(const bf16x8*)(bp + (size_t)(kc * 2 + 1) * 512);
            acc0 = __builtin_amdgcn_mfma_f32_16x16x32_bf16(af, b0, acc0, 0, 0, 0);
            acc1 = __builtin_amdgcn_mfma_f32_16x16x32_bf16(af, b1, acc1, 0, 0, 0);
        }
    }
    if (kh == 1) {
        *(f32x4*)&accred[((rf * 2 + 0) * 64 + lane) * 4] = acc0;
        *(f32x4*)&accred[((rf * 2 + 1) * 64 + lane) * 4] = acc1;
    }
    __syncthreads();

    if (kh == 0) {
        // ---- epilogue ----
        acc0 += *(const f32x4*)&accred[((rf * 2 + 0) * 64 + lane) * 4];
        acc1 += *(const f32x4*)&accred[((rf * 2 + 1) * 64 + lane) * 4];
        const int lq = lane & 15;
        const int rl0 = rf * 16 + ((lane >> 4) << 2);
        float nhv[2][4];
        int uu[2];
        f32x4 accs[2] = {acc0, acc1};
#pragma unroll
        for (int cf = 0; cf < 2; ++cf) {
            const int col = cs * 32 + cf * 16 + lq;
            const int u = col >> 2, g = col & 3;
            uu[cf] = u;
            const float bias = bias4[g * 1024 + u];
#pragma unroll
            for (int reg = 0; reg < 4; ++reg) {
                const int rl = rl0 + reg;
                const int r = rh * 64 + rl;
                union { int4 v; unsigned short us[8]; } a0u, a1u;
                const int4* awv = (const int4*)&AW[((size_t)r * 4096 + col) * 16];
                a0u.v = awv[0]; a1u.v = awv[1];
                float aextra = 0.f;
#pragma unroll
                for (int p = 0; p < 8; ++p) aextra += wlds[rl][p] * bf2f(a0u.us[p]);
#pragma unroll
                for (int p = 0; p < 8; ++p) aextra += wlds[rl][8 + p] * bf2f(a1u.us[p]);
                float a = accs[cf][reg] + bias + aextra;
                float v1 = __shfl_xor(a, 1);
                float v2 = __shfl_xor(a, 2);
                float v3 = __shfl_xor(a, 3);
                auto pick = [&](int m) { return m == 0 ? a : m == 1 ? v1 : m == 2 ? v2 : v3; };
                float ii = sigf(pick(g));
                float ff = sigf(pick(g ^ 1));
                float oo = sigf(pick(g ^ 2));
                float gg = tanhf(pick(g ^ 3));
                const float cold = cst[r * 1024 + u];
                const float nc = ff * cold + ii * gg;
                const float nh = oo * tanhf(nc);
                nhv[cf][reg] = nh;
                if (g == 0) {
                    cst[r * 1024 + u] = nc;
                } else if (g == 1) {
                    const int rfg2 = r >> 4, kc2 = u >> 5,
                              l2 = (r & 15) | (((u >> 3) & 3) << 4);
                    hFout[(size_t)((rfg2 * 32 + kc2) * 64 + l2) * 8 + (u & 7)] = f2bf(nh);
                } else if (g == 3) {
                    out[((size_t)r * 128 + ts) * 1024 + u] = nh;
                }
            }
        }
        // next-step score partials (g==2 lanes; shfl partners all active)
        if ((lane & 3) == 2) {
#pragma unroll
            for (int reg = 0; reg < 4; ++reg) {
                const int r = rh * 64 + rl0 + reg;
                const float n0 = nhv[0][reg], n1 = nhv[1][reg];
                const float4* A0 = (const float4*)&Ag[((size_t)r * 1024 + uu[0]) * 16];
                const float4* A1 = (const float4*)&Ag[((size_t)r * 1024 + uu[1]) * 16];
                float contrib[16];
#pragma unroll
                for (int q = 0; q < 4; ++q) {
                    float4 c0 = A0[q], c1 = A1[q];
                    contrib[q * 4 + 0] = n0 * c0.x + n1 * c1.x;
                    contrib[q * 4 + 1] = n0 * c0.y + n1 * c1.y;
                    contrib[q * 4 + 2] = n0 * c0.z + n1 * c1.z;
                    contrib[q * 4 + 3] = n0 * c0.w + n1 * c1.w;
                }
#pragma unroll
                for (int p = 0; p < 16; ++p) {
                    contrib[p] += __shfl_xor(contrib[p], 4);
                    contrib[p] += __shfl_xor(contrib[p], 8);
                }
                if (lq == 2) {
                    float4* dst = (float4*)&spout[((size_t)cs * 128 + r) * 16];
                    dst[0] = make_float4(contrib[0], contrib[1], contrib[2], contrib[3]);
                    dst[1] = make_float4(contrib[4], contrib[5], contrib[6], contrib[7]);
                    dst[2] = make_float4(contrib[8], contrib[9], contrib[10], contrib[11]);
                    dst[3] = make_float4(contrib[12], contrib[13], contrib[14], contrib[15]);
                }
            }
        }
    } else if (ts + 1 < 128 && tid >= 256 && tid < 320) {
        // pack x[:, ts+1] into xfout (64 of 16384 int4-slots per block)
        const int slot = bid * 64 + (tid - 256);
        const int n = slot >> 7, js = slot & 127, j0 = js * 8;
        const float4* xp = (const float4*)&x[((size_t)n * 128 + (ts + 1)) * 1024 + j0];
        float4 x0 = xp[0], x1 = xp[1];
        unsigned short v[8] = {f2bf(x0.x), f2bf(x0.y), f2bf(x0.z), f2bf(x0.w),
                               f2bf(x1.x), f2bf(x1.y), f2bf(x1.z), f2bf(x1.w)};
        const int rfg2 = n >> 4, kc = j0 >> 5, l = (n & 15) | (((j0 >> 3) & 3) << 4);
        *(int4*)&xfout[(size_t)((rfg2 * 32 + kc) * 64 + l) * 8] = *(const int4*)v;
    }
}

extern "C" void kernel_launch(void* const* d_in, const int* in_sizes, int n_in,
                              void* d_out, int out_size, void* d_ws, size_t ws_size,
                              hipStream_t stream) {
    const float* x     = (const float*)d_in[0];   // (128,128,1024)
    const float* A     = (const float*)d_in[1];   // (128,1024,4,4)
    const float* Wx    = (const float*)d_in[2];   // (1024,4096)
    const float* Wh    = (const float*)d_in[3];   // (1024,4096)
    const float* Wattn = (const float*)d_in[4];   // (1024,4096)
    const float* b     = (const float*)d_in[5];   // (4096,)
    float* out = (float*)d_out;                   // (128,128,1024) f32

    char* ws = (char*)d_ws;
    unsigned short* WTf = (unsigned short*)(ws);                // 16 MB
    unsigned short* AW  = (unsigned short*)(ws + 16777216);     // 16 MB
    unsigned short* hF0 = (unsigned short*)(ws + 33554432);     // 256 KB
    unsigned short* hF1 = (unsigned short*)(ws + 33816576);     // 256 KB
    unsigned short* xfA = (unsigned short*)(ws + 34078720);     // 256 KB
    unsigned short* xfB = (unsigned short*)(ws + 34340864);     // 256 KB
    float* sp0 = (float*)(ws + 34603008);                       // 1 MB
    float* sp1 = (float*)(ws + 35651584);                       // 1 MB
    float* cst = (float*)(ws + 36700160);                       // 512 KB

    k_build_wtf2<<<dim3(64, 32), 256, 0, stream>>>(Wh, Wx, WTf);
    k_build_aw<<<dim3(32, 8), 512, 65536, stream>>>(Wattn, A, AW);
    k_init<<<128, 512, 0, stream>>>(A, x, cst, hF0, xfA, sp0);

    for (int ts = 0; ts < 128; ++ts) {
        unsigned short* hin  = (ts & 1) ? hF1 : hF0;
        unsigned short* hout = (ts & 1) ? hF0 : hF1;
        unsigned short* xin  = (ts & 1) ? xfB : xfA;
        unsigned short* xout = (ts & 1) ? xfA : xfB;
        float* spin  = (ts & 1) ? sp1 : sp0;
        float* spout = (ts & 1) ? sp0 : sp1;
        k_step<<<256, 512, 0, stream>>>(WTf, AW, hin, hout, xin, xout,
                                        spin, spout, cst, A, x, b, out, ts);
    }
}

// Round 5
// 3527.724 us; speedup vs baseline: 3.2411x; 1.2357x over previous
//
#include <hip/hip_runtime.h>
#include <hip/hip_bf16.h>

// N=128, T=128, D=1024, H=1024, 4H=4096.
// Serial GEMM K = 2048: act = [h | x], weights = [Wh | Wx] (reordered cols).
// Reordered col c = 4*unit + gate  <->  orig col j = gate*1024 + unit.
// attn@Wattn = rank-16 update: AW[n][c][p] = sum_u A[n,u,p]*Wattn[u,j(c)].
// scores s[n,p] = sum_u h[n,u]*A[n,u,p]: per-block partials sp[cs][n][p] written
// by step t-1's epilogue; reduced+softmaxed by per-step k_soft into w_ws[n][16].
// One k_soft + one k_step launch per step; launch boundary = global sync.

typedef __bf16 bf16x8 __attribute__((ext_vector_type(8)));
typedef float f32x4 __attribute__((ext_vector_type(4)));

__device__ __forceinline__ unsigned short f2bf(float f) {
    unsigned int u = __float_as_uint(f);
    u += 0x7FFFu + ((u >> 16) & 1u);   // round-to-nearest-even
    return (unsigned short)(u >> 16);
}
__device__ __forceinline__ float bf2f(unsigned short u) {
    return __uint_as_float(((unsigned int)u) << 16);
}
__device__ __forceinline__ float sigf(float x) { return 1.0f / (1.0f + expf(-x)); }

// ---------------------------------------------------------------------------
// WTf: fragment-linear bf16 weight image, K=2048, [Wh | Wx].
// slot(s in [0,128), ks in [0,64), cf in {0,1}, l in [0,64)) holds 8 bf16:
//   col = s*32 + cf*16 + (l&15), k = ks*32 + (l>>4)*8 + i.
// ---------------------------------------------------------------------------
__global__ __launch_bounds__(256) void k_build_wtf2(
    const float* __restrict__ Wh, const float* __restrict__ Wx,
    unsigned short* __restrict__ WTf) {
    __shared__ float tile[64][65];
    const int cs2 = blockIdx.x;   // 64: cols [cs2*64, +64)
    const int kq  = blockIdx.y;   // 32: k [kq*64, +64)
    const int tid = threadIdx.x;
#pragma unroll
    for (int it = 0; it < 16; ++it) {
        int idx = it * 256 + tid;
        int kl = idx >> 6, cl = idx & 63;
        int col = cs2 * 64 + cl;
        int j = (col & 3) * 1024 + (col >> 2);
        int k = kq * 64 + kl;
        tile[kl][cl] = (k < 1024) ? Wh[(size_t)k * 4096 + j]
                                  : Wx[(size_t)(k - 1024) * 4096 + j];
    }
    __syncthreads();
#pragma unroll
    for (int it = 0; it < 2; ++it) {
        int slotid = it * 256 + tid;        // 512 slots
        int l   = slotid & 63;
        int cf  = (slotid >> 6) & 1;
        int ksl = (slotid >> 7) & 1;
        int sl  = slotid >> 8;
        int s = cs2 * 2 + sl, ks = kq * 2 + ksl;
        int clocal = sl * 32 + cf * 16 + (l & 15);
        int klocal = ksl * 32 + ((l >> 4) << 3);
        unsigned short v[8];
#pragma unroll
        for (int i = 0; i < 8; ++i) v[i] = f2bf(tile[klocal + i][clocal]);
        *(int4*)&WTf[(size_t)(((s * 64 + ks) * 2 + cf) * 64 + l) * 8] = *(const int4*)v;
    }
}

// ---------------------------------------------------------------------------
// WAf: fragment-linear bf16 image of Wattn (reordered cols), K=1024.
// slot(s in [0,128), ks in [0,32), cf, l): col = s*32+cf*16+(l&15),
// k = ks*32+(l>>4)*8+i.
// ---------------------------------------------------------------------------
__global__ __launch_bounds__(256) void k_build_waf(
    const float* __restrict__ Wattn, unsigned short* __restrict__ WAf) {
    __shared__ float tile[64][65];
    const int cs2 = blockIdx.x;   // 64
    const int kq  = blockIdx.y;   // 16
    const int tid = threadIdx.x;
#pragma unroll
    for (int it = 0; it < 16; ++it) {
        int idx = it * 256 + tid;
        int kl = idx >> 6, cl = idx & 63;
        int col = cs2 * 64 + cl;
        int j = (col & 3) * 1024 + (col >> 2);
        int k = kq * 64 + kl;
        tile[kl][cl] = Wattn[(size_t)k * 4096 + j];
    }
    __syncthreads();
#pragma unroll
    for (int it = 0; it < 2; ++it) {
        int slotid = it * 256 + tid;
        int l   = slotid & 63;
        int cf  = (slotid >> 6) & 1;
        int ksl = (slotid >> 7) & 1;
        int sl  = slotid >> 8;
        int s = cs2 * 2 + sl, ks = kq * 2 + ksl;
        int clocal = sl * 32 + cf * 16 + (l & 15);
        int klocal = ksl * 32 + ((l >> 4) << 3);
        unsigned short v[8];
#pragma unroll
        for (int i = 0; i < 8; ++i) v[i] = f2bf(tile[klocal + i][clocal]);
        *(int4*)&WAf[(size_t)(((s * 32 + ks) * 2 + cf) * 64 + l) * 8] = *(const int4*)v;
    }
}

// ---------------------------------------------------------------------------
// ATf[n]: frag-linear bf16 A^T per n (M=p dim 16, K=u dim 1024).
// slot (n, kc in [0,32), l): holds A[n][kc*32+(l>>4)*8+i][l&15].
// ---------------------------------------------------------------------------
__global__ __launch_bounds__(256) void k_pack_at(
    const float* __restrict__ Ag, unsigned short* __restrict__ ATf) {
    __shared__ unsigned short lds[1024][17];
    const int n = blockIdx.x;
    const int tid = threadIdx.x;
#pragma unroll
    for (int it = 0; it < 16; ++it) {
        int idx = it * 256 + tid;          // 4096 float4
        const float4 v = ((const float4*)(Ag + (size_t)n * 16384))[idx];
        int flat = idx * 4;
        int u = flat >> 4, p = flat & 15;
        lds[u][p + 0] = f2bf(v.x); lds[u][p + 1] = f2bf(v.y);
        lds[u][p + 2] = f2bf(v.z); lds[u][p + 3] = f2bf(v.w);
    }
    __syncthreads();
#pragma unroll
    for (int it = 0; it < 8; ++it) {
        int slot = it * 256 + tid;         // 2048
        int kc = slot >> 6, l = slot & 63;
        int ubase = kc * 32 + ((l >> 4) << 3);
        int p = l & 15;
        unsigned short v[8];
#pragma unroll
        for (int i = 0; i < 8; ++i) v[i] = lds[ubase + i][p];
        *(int4*)&ATf[((size_t)n * 2048 + slot) * 8] = *(const int4*)v;
    }
}

// ---------------------------------------------------------------------------
// AW[n][c][p] = sum_u A[n,u,p] * Wattn[u,j(c)] via MFMA.
// Grid (16 ng, 32 ct), 512 threads (8 waves). Block: 8 n x 128 cols, K=1024.
// Wave w: 16 cols (s = ct*4 + (w>>1), cf = w&1), 8 row-frags (nn).
// ---------------------------------------------------------------------------
__global__ __launch_bounds__(512) void k_aw_gemm(
    const unsigned short* __restrict__ ATf, const unsigned short* __restrict__ WAf,
    unsigned short* __restrict__ AW) {
    const int ng = blockIdx.x;        // 16: n in [ng*8, +8)
    const int ct = blockIdx.y;        // 32: cols [ct*128, +128)
    const int tid = threadIdx.x;
    const int lane = tid & 63, wave = tid >> 6;
    const int s = ct * 4 + (wave >> 1), cf = wave & 1;
    const int n0 = ng * 8;
    f32x4 acc[8] = {};
    const unsigned short* bp = WAf + ((size_t)((s * 32) * 2 + cf) * 64 + lane) * 8;
    const unsigned short* ap = ATf + ((size_t)n0 * 2048 + lane) * 8;
#pragma unroll 4
    for (int kc = 0; kc < 32; ++kc) {
        bf16x8 bf = *(const bf16x8*)(bp + (size_t)kc * 1024);
#pragma unroll
        for (int nn = 0; nn < 8; ++nn) {
            bf16x8 af = *(const bf16x8*)(ap + (size_t)nn * 16384 + (size_t)kc * 512);
            acc[nn] = __builtin_amdgcn_mfma_f32_16x16x32_bf16(af, bf, acc[nn], 0, 0, 0);
        }
    }
    const int col = ct * 128 + wave * 16 + (lane & 15);
    const int prow = (lane >> 4) << 2;
#pragma unroll
    for (int nn = 0; nn < 8; ++nn) {
#pragma unroll
        for (int reg = 0; reg < 4; ++reg) {
            AW[((size_t)(n0 + nn) * 4096 + col) * 16 + prow + reg] = f2bf(acc[nn][reg]);
        }
    }
}

// ---------------------------------------------------------------------------
// Fallback (slow, ws-lean) AW builder — used only if ws_size is too small.
// ---------------------------------------------------------------------------
__global__ __launch_bounds__(512) void k_build_aw(
    const float* __restrict__ Wattn, const float* __restrict__ Ag,
    unsigned short* __restrict__ AW) {
    extern __shared__ float Alds[];   // [1024][16] f32 = 64KB
    const int jt = blockIdx.x;        // 32
    const int ng = blockIdx.y;        // 8
    const int tid = threadIdx.x;
    const int jl = tid & 127, pg = tid >> 7;
    const int jj = jt * 128 + jl;
    for (int nn = 0; nn < 16; ++nn) {
        const int n = ng * 16 + nn;
        __syncthreads();
#pragma unroll
        for (int q = 0; q < 8; ++q) {
            int idx = q * 512 + tid;
            ((float4*)Alds)[idx] = ((const float4*)(Ag + (size_t)n * 16384))[idx];
        }
        __syncthreads();
        f32x4 acc = {0.f, 0.f, 0.f, 0.f};
#pragma unroll 8
        for (int u = 0; u < 1024; ++u) {
            float wv = Wattn[(size_t)u * 4096 + jj];
            const float4 av = *(const float4*)&Alds[u * 16 + pg * 4];
            acc[0] += wv * av.x; acc[1] += wv * av.y;
            acc[2] += wv * av.z; acc[3] += wv * av.w;
        }
        const int g = jj >> 10, unit = jj & 1023;
        const int cre = unit * 4 + g;
        ushort4 st = make_ushort4(f2bf(acc[0]), f2bf(acc[1]), f2bf(acc[2]), f2bf(acc[3]));
        *(ushort4*)&AW[((size_t)n * 4096 + cre) * 16 + pg * 4] = st;
    }
}

// ---------------------------------------------------------------------------
// h0 = c0 = mean over 16 positions of A. Writes cst, hF0, xf0, sp0 partials.
// ---------------------------------------------------------------------------
__global__ __launch_bounds__(512) void k_init(
    const float* __restrict__ Ag, const float* __restrict__ x,
    float* __restrict__ cst, unsigned short* __restrict__ hF0,
    unsigned short* __restrict__ xf0, float* __restrict__ sp) {
    const int n = blockIdx.x;
    const int t = threadIdx.x;
    if (t < 128) {
        const int j0 = t * 8;
        const float4* xp = (const float4*)&x[((size_t)n * 128 + 0) * 1024 + j0];
        float4 x0 = xp[0], x1 = xp[1];
        unsigned short v[8] = {f2bf(x0.x), f2bf(x0.y), f2bf(x0.z), f2bf(x0.w),
                               f2bf(x1.x), f2bf(x1.y), f2bf(x1.z), f2bf(x1.w)};
        const int rfg = n >> 4, kc = j0 >> 5, l = (n & 15) | (((j0 >> 3) & 3) << 4);
        *(int4*)&xf0[(size_t)((rfg * 32 + kc) * 64 + l) * 8] = *(const int4*)v;
    }
    float contrib[16];
#pragma unroll
    for (int p = 0; p < 16; ++p) contrib[p] = 0.f;
#pragma unroll
    for (int e = 0; e < 2; ++e) {
        const int u = t * 2 + e;
        const float4* ap = (const float4*)&Ag[((size_t)n * 1024 + u) * 16];
        float4 a0 = ap[0], a1 = ap[1], a2 = ap[2], a3 = ap[3];
        float s = a0.x + a0.y + a0.z + a0.w + a1.x + a1.y + a1.z + a1.w +
                  a2.x + a2.y + a2.z + a2.w + a3.x + a3.y + a3.z + a3.w;
        float h0 = s * (1.0f / 16.0f);
        cst[n * 1024 + u] = h0;
        const int rfg = n >> 4, kc = u >> 5, l = (n & 15) | (((u >> 3) & 3) << 4);
        hF0[(size_t)((rfg * 32 + kc) * 64 + l) * 8 + (u & 7)] = f2bf(h0);
        contrib[0]  += h0 * a0.x;  contrib[1]  += h0 * a0.y;
        contrib[2]  += h0 * a0.z;  contrib[3]  += h0 * a0.w;
        contrib[4]  += h0 * a1.x;  contrib[5]  += h0 * a1.y;
        contrib[6]  += h0 * a1.z;  contrib[7]  += h0 * a1.w;
        contrib[8]  += h0 * a2.x;  contrib[9]  += h0 * a2.y;
        contrib[10] += h0 * a2.z;  contrib[11] += h0 * a2.w;
        contrib[12] += h0 * a3.x;  contrib[13] += h0 * a3.y;
        contrib[14] += h0 * a3.z;  contrib[15] += h0 * a3.w;
    }
#pragma unroll
    for (int p = 0; p < 16; ++p) {
        contrib[p] += __shfl_xor(contrib[p], 1);
        contrib[p] += __shfl_xor(contrib[p], 2);
    }
    if ((t & 3) == 0) {
        const int cs = t >> 2;
        float4* dst = (float4*)&sp[((size_t)cs * 128 + n) * 16];
        dst[0] = make_float4(contrib[0], contrib[1], contrib[2], contrib[3]);
        dst[1] = make_float4(contrib[4], contrib[5], contrib[6], contrib[7]);
        dst[2] = make_float4(contrib[8], contrib[9], contrib[10], contrib[11]);
        dst[3] = make_float4(contrib[12], contrib[13], contrib[14], contrib[15]);
    }
}

// ---------------------------------------------------------------------------
// Per-step score reduce + softmax: w_ws[n][16] from sp partials (fixed order).
// 128 blocks x 64 threads. Lane = q*16+p; each lane sums 32 cs-slices.
// ---------------------------------------------------------------------------
__global__ __launch_bounds__(64) void k_soft(
    const float* __restrict__ spin, float* __restrict__ w_ws) {
    const int n = blockIdx.x;
    const int lane = threadIdx.x;
    const int p = lane & 15, q = lane >> 4;
    float s = 0.f;
    const float* base = &spin[(size_t)(q * 32) * 2048 + n * 16 + p];
#pragma unroll 8
    for (int i = 0; i < 32; ++i) s += base[(size_t)i * 2048];
    s += __shfl_xor(s, 16);
    s += __shfl_xor(s, 32);
    float mx = s;
#pragma unroll
    for (int m = 1; m < 16; m <<= 1) mx = fmaxf(mx, __shfl_xor(mx, m));
    float e = expf((s - mx) * 0.03125f);
    float se = e;
#pragma unroll
    for (int m = 1; m < 16; m <<= 1) se += __shfl_xor(se, m);
    if (lane < 16) w_ws[n * 16 + p] = e / se;
}

// ---------------------------------------------------------------------------
// One time step. 256 blocks x 512 threads. Block (cs = bid>>1, rh = bid&1):
// 64 rows x 32 reordered cols, K=2048 split over kh wave-halves.
// Prologue: load w_ws -> wlds (4KB). GEMM frag-linear, no barrier. One barrier
// for cross-kh accumulate. Epilogue (kh==0): bias + rank-16 attn + gates +
// state update + out + next-step sp partials. kh==1 waves pack x for ts+1.
// ---------------------------------------------------------------------------
__global__ __launch_bounds__(512) void k_step(
    const unsigned short* __restrict__ WTf, const unsigned short* __restrict__ AW,
    const unsigned short* __restrict__ hFin, unsigned short* __restrict__ hFout,
    const unsigned short* __restrict__ xfin, unsigned short* __restrict__ xfout,
    const float* __restrict__ w_ws, float* __restrict__ spout,
    float* __restrict__ cst, const float* __restrict__ Ag,
    const float* __restrict__ x, const float* __restrict__ bias4,
    float* __restrict__ out, int ts) {
    __shared__ float wlds[64][17];        // 4.25 KB
    __shared__ float accred[2048];        // 8 KB
    const int bid = blockIdx.x;
    const int cs = bid >> 1, rh = bid & 1;
    const int tid = threadIdx.x;
    const int lane = tid & 63, wave = tid >> 6;

    // ---- prologue: load softmax weights for this block's 64 rows ----
#pragma unroll
    for (int it = 0; it < 2; ++it) {
        const int idx = it * 512 + tid;   // 1024 = 64 nl x 16 p
        const int nl = idx >> 4, p = idx & 15;
        wlds[nl][p] = w_ws[(rh * 64 + nl) * 16 + p];
    }

    // ---- GEMM (no barrier inside) ----
    const int rf = wave & 3, kh = wave >> 2;
    const int rfg = rh * 4 + rf;
    f32x4 acc0 = {0.f, 0.f, 0.f, 0.f}, acc1 = {0.f, 0.f, 0.f, 0.f};
    {
        const unsigned short* aptr = (kh == 0)
            ? hFin + (size_t)rfg * 32 * 512 + lane * 8
            : xfin + (size_t)rfg * 32 * 512 + lane * 8;
        const unsigned short* bp = WTf + (size_t)(cs * 64 + kh * 32) * 2 * 512 + lane * 8;
#pragma unroll 4
        for (int kc = 0; kc < 32; ++kc) {
            bf16x8 af = *(const bf16x8*)(aptr + (size_t)kc * 512);
            bf16x8 b0 = *(const bf16x8*)(bp + (size_t)(kc * 2) * 512);
            bf16x8 b1 = *(const bf16x8*)(bp + (size_t)(kc * 2 + 1) * 512);
            acc0 = __builtin_amdgcn_mfma_f32_16x16x32_bf16(af, b0, acc0, 0, 0, 0);
            acc1 = __builtin_amdgcn_mfma_f32_16x16x32_bf16(af, b1, acc1, 0, 0, 0);
        }
    }
    if (kh == 1) {
        *(f32x4*)&accred[((rf * 2 + 0) * 64 + lane) * 4] = acc0;
        *(f32x4*)&accred[((rf * 2 + 1) * 64 + lane) * 4] = acc1;
    }
    __syncthreads();

    if (kh == 0) {
        // ---- epilogue ----
        acc0 += *(const f32x4*)&accred[((rf * 2 + 0) * 64 + lane) * 4];
        acc1 += *(const f32x4*)&accred[((rf * 2 + 1) * 64 + lane) * 4];
        const int lq = lane & 15;
        const int rl0 = rf * 16 + ((lane >> 4) << 2);
        float nhv[2][4];
        int uu[2];
        f32x4 accs[2] = {acc0, acc1};
#pragma unroll
        for (int cf = 0; cf < 2; ++cf) {
            const int col = cs * 32 + cf * 16 + lq;
            const int u = col >> 2, g = col & 3;
            uu[cf] = u;
            const float bias = bias4[g * 1024 + u];
#pragma unroll
            for (int reg = 0; reg < 4; ++reg) {
                const int rl = rl0 + reg;
                const int r = rh * 64 + rl;
                union { int4 v; unsigned short us[8]; } a0u, a1u;
                const int4* awv = (const int4*)&AW[((size_t)r * 4096 + col) * 16];
                a0u.v = awv[0]; a1u.v = awv[1];
                float aextra = 0.f;
#pragma unroll
                for (int p = 0; p < 8; ++p) aextra += wlds[rl][p] * bf2f(a0u.us[p]);
#pragma unroll
                for (int p = 0; p < 8; ++p) aextra += wlds[rl][8 + p] * bf2f(a1u.us[p]);
                float a = accs[cf][reg] + bias + aextra;
                float v1 = __shfl_xor(a, 1);
                float v2 = __shfl_xor(a, 2);
                float v3 = __shfl_xor(a, 3);
                auto pick = [&](int m) { return m == 0 ? a : m == 1 ? v1 : m == 2 ? v2 : v3; };
                float ii = sigf(pick(g));
                float ff = sigf(pick(g ^ 1));
                float oo = sigf(pick(g ^ 2));
                float gg = tanhf(pick(g ^ 3));
                const float cold = cst[r * 1024 + u];
                const float nc = ff * cold + ii * gg;
                const float nh = oo * tanhf(nc);
                nhv[cf][reg] = nh;
                if (g == 0) {
                    cst[r * 1024 + u] = nc;
                } else if (g == 1) {
                    const int rfg2 = r >> 4, kc2 = u >> 5,
                              l2 = (r & 15) | (((u >> 3) & 3) << 4);
                    hFout[(size_t)((rfg2 * 32 + kc2) * 64 + l2) * 8 + (u & 7)] = f2bf(nh);
                } else if (g == 3) {
                    out[((size_t)r * 128 + ts) * 1024 + u] = nh;
                }
            }
        }
        // next-step score partials (g==2 lanes; shfl partners all active)
        if ((lane & 3) == 2) {
#pragma unroll
            for (int reg = 0; reg < 4; ++reg) {
                const int r = rh * 64 + rl0 + reg;
                const float n0 = nhv[0][reg], n1 = nhv[1][reg];
                const float4* A0 = (const float4*)&Ag[((size_t)r * 1024 + uu[0]) * 16];
                const float4* A1 = (const float4*)&Ag[((size_t)r * 1024 + uu[1]) * 16];
                float contrib[16];
#pragma unroll
                for (int q = 0; q < 4; ++q) {
                    float4 c0 = A0[q], c1 = A1[q];
                    contrib[q * 4 + 0] = n0 * c0.x + n1 * c1.x;
                    contrib[q * 4 + 1] = n0 * c0.y + n1 * c1.y;
                    contrib[q * 4 + 2] = n0 * c0.z + n1 * c1.z;
                    contrib[q * 4 + 3] = n0 * c0.w + n1 * c1.w;
                }
#pragma unroll
                for (int p = 0; p < 16; ++p) {
                    contrib[p] += __shfl_xor(contrib[p], 4);
                    contrib[p] += __shfl_xor(contrib[p], 8);
                }
                if (lq == 2) {
                    float4* dst = (float4*)&spout[((size_t)cs * 128 + r) * 16];
                    dst[0] = make_float4(contrib[0], contrib[1], contrib[2], contrib[3]);
                    dst[1] = make_float4(contrib[4], contrib[5], contrib[6], contrib[7]);
                    dst[2] = make_float4(contrib[8], contrib[9], contrib[10], contrib[11]);
                    dst[3] = make_float4(contrib[12], contrib[13], contrib[14], contrib[15]);
                }
            }
        }
    } else if (ts + 1 < 128 && tid >= 256 && tid < 320) {
        // pack x[:, ts+1] into xfout
        const int slot = bid * 64 + (tid - 256);
        const int n = slot >> 7, js = slot & 127, j0 = js * 8;
        const float4* xp = (const float4*)&x[((size_t)n * 128 + (ts + 1)) * 1024 + j0];
        float4 x0 = xp[0], x1 = xp[1];
        unsigned short v[8] = {f2bf(x0.x), f2bf(x0.y), f2bf(x0.z), f2bf(x0.w),
                               f2bf(x1.x), f2bf(x1.y), f2bf(x1.z), f2bf(x1.w)};
        const int rfg2 = n >> 4, kc = j0 >> 5, l = (n & 15) | (((j0 >> 3) & 3) << 4);
        *(int4*)&xfout[(size_t)((rfg2 * 32 + kc) * 64 + l) * 8] = *(const int4*)v;
    }
}

extern "C" void kernel_launch(void* const* d_in, const int* in_sizes, int n_in,
                              void* d_out, int out_size, void* d_ws, size_t ws_size,
                              hipStream_t stream) {
    const float* x     = (const float*)d_in[0];   // (128,128,1024)
    const float* A     = (const float*)d_in[1];   // (128,1024,4,4)
    const float* Wx    = (const float*)d_in[2];   // (1024,4096)
    const float* Wh    = (const float*)d_in[3];   // (1024,4096)
    const float* Wattn = (const float*)d_in[4];   // (1024,4096)
    const float* b     = (const float*)d_in[5];   // (4096,)
    float* out = (float*)d_out;                   // (128,128,1024) f32

    char* ws = (char*)d_ws;
    unsigned short* WTf = (unsigned short*)(ws);                // 16 MB
    unsigned short* AW  = (unsigned short*)(ws + 16777216);     // 16 MB
    // small persistent state (written by k_init AFTER the aw build):
    unsigned short* hF0 = (unsigned short*)(ws + 33554432);     // 256 KB
    unsigned short* hF1 = (unsigned short*)(ws + 33816576);     // 256 KB
    unsigned short* xfA = (unsigned short*)(ws + 34078720);     // 256 KB
    unsigned short* xfB = (unsigned short*)(ws + 34340864);     // 256 KB
    float* sp0 = (float*)(ws + 34603008);                       // 1 MB
    float* sp1 = (float*)(ws + 35651584);                       // 1 MB
    float* cst = (float*)(ws + 36700160);                       // 512 KB
    float* w_ws = (float*)(ws + 37224448);                      // 8 KB
    // transient build buffers, aliased over the small-state region (used
    // strictly before k_init in stream order; rebuilt every call):
    unsigned short* ATf = (unsigned short*)(ws + 33554432);     // 4 MB
    unsigned short* WAf = (unsigned short*)(ws + 37748736);     // 8 MB -> end 44 MB

    k_build_wtf2<<<dim3(64, 32), 256, 0, stream>>>(Wh, Wx, WTf);
    if (ws_size >= 46137344u) {
        k_build_waf<<<dim3(64, 16), 256, 0, stream>>>(Wattn, WAf);
        k_pack_at<<<128, 256, 0, stream>>>(A, ATf);
        k_aw_gemm<<<dim3(16, 32), 512, 0, stream>>>(ATf, WAf, AW);
    } else {
        k_build_aw<<<dim3(32, 8), 512, 65536, stream>>>(Wattn, A, AW);
    }
    k_init<<<128, 512, 0, stream>>>(A, x, cst, hF0, xfA, sp0);

    for (int ts = 0; ts < 128; ++ts) {
        unsigned short* hin  = (ts & 1) ? hF1 : hF0;
        unsigned short* hout = (ts & 1) ? hF0 : hF1;
        unsigned short* xin  = (ts & 1) ? xfB : xfA;
        unsigned short* xout = (ts & 1) ? xfA : xfB;
        float* spin  = (ts & 1) ? sp1 : sp0;
        float* spout = (ts & 1) ? sp0 : sp1;
        k_soft<<<128, 64, 0, stream>>>(spin, w_ws);
        k_step<<<256, 512, 0, stream>>>(WTf, AW, hin, hout, xin, xout,
                                        w_ws, spout, cst, A, x, b, out, ts);
    }
}

// Round 6
// 2561.067 us; speedup vs baseline: 4.4645x; 1.3774x over previous
//
#include <hip/hip_runtime.h>
#include <hip/hip_bf16.h>

// N=128, T=128, D=1024, H=1024, 4H=4096.
// Serial GEMM K = 2048: act = [h | x], weights = [Wh | Wx] (reordered cols).
// Reordered col c = 4*unit + gate  <->  orig col j = gate*1024 + unit.
// attn@Wattn = rank-16 update: AW[n][c][p] = sum_u A[n,u,p]*Wattn[u,j(c)].
// scores s[n,p] = sum_u h[n,u]*A[n,u,p]: per-(32col,kh)-slice partials
// sp[r][256][16] written by step t-1's epilogue; reduced+softmaxed by k_soft.
// One k_soft + one k_step launch per step; launch boundary = global sync.

typedef __bf16 bf16x8 __attribute__((ext_vector_type(8)));
typedef float f32x4 __attribute__((ext_vector_type(4)));

__device__ __forceinline__ unsigned short f2bf(float f) {
    unsigned int u = __float_as_uint(f);
    u += 0x7FFFu + ((u >> 16) & 1u);   // round-to-nearest-even
    return (unsigned short)(u >> 16);
}
__device__ __forceinline__ float bf2f(unsigned short u) {
    return __uint_as_float(((unsigned int)u) << 16);
}
__device__ __forceinline__ float sigf(float x) { return 1.0f / (1.0f + __expf(-x)); }
__device__ __forceinline__ float tanhf_fast(float x) {
    const float t = __expf(-2.0f * fabsf(x));   // in (0,1], no overflow
    const float r = (1.0f - t) / (1.0f + t);
    return copysignf(r, x);
}

// ---------------------------------------------------------------------------
// WTf: fragment-linear bf16 weight image, K=2048, [Wh | Wx].
// slot(s in [0,128), ks in [0,64), cf in {0,1}, l in [0,64)) holds 8 bf16:
//   col = s*32 + cf*16 + (l&15), k = ks*32 + (l>>4)*8 + i.
// ---------------------------------------------------------------------------
__global__ __launch_bounds__(256) void k_build_wtf2(
    const float* __restrict__ Wh, const float* __restrict__ Wx,
    unsigned short* __restrict__ WTf) {
    __shared__ float tile[64][65];
    const int cs2 = blockIdx.x;   // 64: cols [cs2*64, +64)
    const int kq  = blockIdx.y;   // 32: k [kq*64, +64)
    const int tid = threadIdx.x;
#pragma unroll
    for (int it = 0; it < 16; ++it) {
        int idx = it * 256 + tid;
        int kl = idx >> 6, cl = idx & 63;
        int col = cs2 * 64 + cl;
        int j = (col & 3) * 1024 + (col >> 2);
        int k = kq * 64 + kl;
        tile[kl][cl] = (k < 1024) ? Wh[(size_t)k * 4096 + j]
                                  : Wx[(size_t)(k - 1024) * 4096 + j];
    }
    __syncthreads();
#pragma unroll
    for (int it = 0; it < 2; ++it) {
        int slotid = it * 256 + tid;        // 512 slots
        int l   = slotid & 63;
        int cf  = (slotid >> 6) & 1;
        int ksl = (slotid >> 7) & 1;
        int sl  = slotid >> 8;
        int s = cs2 * 2 + sl, ks = kq * 2 + ksl;
        int clocal = sl * 32 + cf * 16 + (l & 15);
        int klocal = ksl * 32 + ((l >> 4) << 3);
        unsigned short v[8];
#pragma unroll
        for (int i = 0; i < 8; ++i) v[i] = f2bf(tile[klocal + i][clocal]);
        *(int4*)&WTf[(size_t)(((s * 64 + ks) * 2 + cf) * 64 + l) * 8] = *(const int4*)v;
    }
}

// ---------------------------------------------------------------------------
// WAf: fragment-linear bf16 image of Wattn (reordered cols), K=1024.
// ---------------------------------------------------------------------------
__global__ __launch_bounds__(256) void k_build_waf(
    const float* __restrict__ Wattn, unsigned short* __restrict__ WAf) {
    __shared__ float tile[64][65];
    const int cs2 = blockIdx.x;   // 64
    const int kq  = blockIdx.y;   // 16
    const int tid = threadIdx.x;
#pragma unroll
    for (int it = 0; it < 16; ++it) {
        int idx = it * 256 + tid;
        int kl = idx >> 6, cl = idx & 63;
        int col = cs2 * 64 + cl;
        int j = (col & 3) * 1024 + (col >> 2);
        int k = kq * 64 + kl;
        tile[kl][cl] = Wattn[(size_t)k * 4096 + j];
    }
    __syncthreads();
#pragma unroll
    for (int it = 0; it < 2; ++it) {
        int slotid = it * 256 + tid;
        int l   = slotid & 63;
        int cf  = (slotid >> 6) & 1;
        int ksl = (slotid >> 7) & 1;
        int sl  = slotid >> 8;
        int s = cs2 * 2 + sl, ks = kq * 2 + ksl;
        int clocal = sl * 32 + cf * 16 + (l & 15);
        int klocal = ksl * 32 + ((l >> 4) << 3);
        unsigned short v[8];
#pragma unroll
        for (int i = 0; i < 8; ++i) v[i] = f2bf(tile[klocal + i][clocal]);
        *(int4*)&WAf[(size_t)(((s * 32 + ks) * 2 + cf) * 64 + l) * 8] = *(const int4*)v;
    }
}

// ---------------------------------------------------------------------------
// ATf[n]: frag-linear bf16 A^T per n (M=p dim 16, K=u dim 1024).
// ---------------------------------------------------------------------------
__global__ __launch_bounds__(256) void k_pack_at(
    const float* __restrict__ Ag, unsigned short* __restrict__ ATf) {
    __shared__ unsigned short lds[1024][17];
    const int n = blockIdx.x;
    const int tid = threadIdx.x;
#pragma unroll
    for (int it = 0; it < 16; ++it) {
        int idx = it * 256 + tid;          // 4096 float4
        const float4 v = ((const float4*)(Ag + (size_t)n * 16384))[idx];
        int flat = idx * 4;
        int u = flat >> 4, p = flat & 15;
        lds[u][p + 0] = f2bf(v.x); lds[u][p + 1] = f2bf(v.y);
        lds[u][p + 2] = f2bf(v.z); lds[u][p + 3] = f2bf(v.w);
    }
    __syncthreads();
#pragma unroll
    for (int it = 0; it < 8; ++it) {
        int slot = it * 256 + tid;         // 2048
        int kc = slot >> 6, l = slot & 63;
        int ubase = kc * 32 + ((l >> 4) << 3);
        int p = l & 15;
        unsigned short v[8];
#pragma unroll
        for (int i = 0; i < 8; ++i) v[i] = lds[ubase + i][p];
        *(int4*)&ATf[((size_t)n * 2048 + slot) * 8] = *(const int4*)v;
    }
}

// ---------------------------------------------------------------------------
// AW[n][c][p] = sum_u A[n,u,p] * Wattn[u,j(c)] via MFMA.
// ---------------------------------------------------------------------------
__global__ __launch_bounds__(512) void k_aw_gemm(
    const unsigned short* __restrict__ ATf, const unsigned short* __restrict__ WAf,
    unsigned short* __restrict__ AW) {
    const int ng = blockIdx.x;        // 16: n in [ng*8, +8)
    const int ct = blockIdx.y;        // 32: cols [ct*128, +128)
    const int tid = threadIdx.x;
    const int lane = tid & 63, wave = tid >> 6;
    const int s = ct * 4 + (wave >> 1), cf = wave & 1;
    const int n0 = ng * 8;
    f32x4 acc[8] = {};
    const unsigned short* bp = WAf + ((size_t)((s * 32) * 2 + cf) * 64 + lane) * 8;
    const unsigned short* ap = ATf + ((size_t)n0 * 2048 + lane) * 8;
#pragma unroll 4
    for (int kc = 0; kc < 32; ++kc) {
        bf16x8 bf = *(const bf16x8*)(bp + (size_t)kc * 1024);
#pragma unroll
        for (int nn = 0; nn < 8; ++nn) {
            bf16x8 af = *(const bf16x8*)(ap + (size_t)nn * 16384 + (size_t)kc * 512);
            acc[nn] = __builtin_amdgcn_mfma_f32_16x16x32_bf16(af, bf, acc[nn], 0, 0, 0);
        }
    }
    const int col = ct * 128 + wave * 16 + (lane & 15);
    const int prow = (lane >> 4) << 2;
#pragma unroll
    for (int nn = 0; nn < 8; ++nn) {
        ushort4 st = make_ushort4(f2bf(acc[nn][0]), f2bf(acc[nn][1]),
                                  f2bf(acc[nn][2]), f2bf(acc[nn][3]));
        *(ushort4*)&AW[((size_t)(n0 + nn) * 4096 + col) * 16 + prow] = st;
    }
}

// ---------------------------------------------------------------------------
// Fallback (slow, ws-lean) AW builder — used only if ws_size is too small.
// ---------------------------------------------------------------------------
__global__ __launch_bounds__(512) void k_build_aw(
    const float* __restrict__ Wattn, const float* __restrict__ Ag,
    unsigned short* __restrict__ AW) {
    extern __shared__ float Alds[];   // 64KB
    const int jt = blockIdx.x;        // 32
    const int ng = blockIdx.y;        // 8
    const int tid = threadIdx.x;
    const int jl = tid & 127, pg = tid >> 7;
    const int jj = jt * 128 + jl;
    for (int nn = 0; nn < 16; ++nn) {
        const int n = ng * 16 + nn;
        __syncthreads();
#pragma unroll
        for (int q = 0; q < 8; ++q) {
            int idx = q * 512 + tid;
            ((float4*)Alds)[idx] = ((const float4*)(Ag + (size_t)n * 16384))[idx];
        }
        __syncthreads();
        f32x4 acc = {0.f, 0.f, 0.f, 0.f};
#pragma unroll 8
        for (int u = 0; u < 1024; ++u) {
            float wv = Wattn[(size_t)u * 4096 + jj];
            const float4 av = *(const float4*)&Alds[u * 16 + pg * 4];
            acc[0] += wv * av.x; acc[1] += wv * av.y;
            acc[2] += wv * av.z; acc[3] += wv * av.w;
        }
        const int g = jj >> 10, unit = jj & 1023;
        const int cre = unit * 4 + g;
        ushort4 st = make_ushort4(f2bf(acc[0]), f2bf(acc[1]), f2bf(acc[2]), f2bf(acc[3]));
        *(ushort4*)&AW[((size_t)n * 4096 + cre) * 16 + pg * 4] = st;
    }
}

// ---------------------------------------------------------------------------
// h0 = c0 = mean over 16 positions of A. Writes cst, hF0, sp0 partials
// (new layout sp[r][256 slices][16]: slices 0..127 get k_init's 8-unit
// partials, slices 128..255 zeroed).
// ---------------------------------------------------------------------------
__global__ __launch_bounds__(512) void k_init(
    const float* __restrict__ Ag, float* __restrict__ cst,
    unsigned short* __restrict__ hF0, float* __restrict__ sp) {
    const int n = blockIdx.x;
    const int t = threadIdx.x;
    float contrib[16];
#pragma unroll
    for (int p = 0; p < 16; ++p) contrib[p] = 0.f;
#pragma unroll
    for (int e = 0; e < 2; ++e) {
        const int u = t * 2 + e;
        const float4* ap = (const float4*)&Ag[((size_t)n * 1024 + u) * 16];
        float4 a0 = ap[0], a1 = ap[1], a2 = ap[2], a3 = ap[3];
        float s = a0.x + a0.y + a0.z + a0.w + a1.x + a1.y + a1.z + a1.w +
                  a2.x + a2.y + a2.z + a2.w + a3.x + a3.y + a3.z + a3.w;
        float h0 = s * (1.0f / 16.0f);
        cst[n * 1024 + u] = h0;
        const int rfg = n >> 4, kc = u >> 5, l = (n & 15) | (((u >> 3) & 3) << 4);
        hF0[(size_t)((rfg * 32 + kc) * 64 + l) * 8 + (u & 7)] = f2bf(h0);
        contrib[0]  += h0 * a0.x;  contrib[1]  += h0 * a0.y;
        contrib[2]  += h0 * a0.z;  contrib[3]  += h0 * a0.w;
        contrib[4]  += h0 * a1.x;  contrib[5]  += h0 * a1.y;
        contrib[6]  += h0 * a1.z;  contrib[7]  += h0 * a1.w;
        contrib[8]  += h0 * a2.x;  contrib[9]  += h0 * a2.y;
        contrib[10] += h0 * a2.z;  contrib[11] += h0 * a2.w;
        contrib[12] += h0 * a3.x;  contrib[13] += h0 * a3.y;
        contrib[14] += h0 * a3.z;  contrib[15] += h0 * a3.w;
    }
#pragma unroll
    for (int p = 0; p < 16; ++p) {
        contrib[p] += __shfl_xor(contrib[p], 1);
        contrib[p] += __shfl_xor(contrib[p], 2);
    }
    if ((t & 3) == 0) {
        const int slice = t >> 2;   // 0..127
        float4* dst = (float4*)&sp[(size_t)n * 4096 + slice * 16];
        dst[0] = make_float4(contrib[0], contrib[1], contrib[2], contrib[3]);
        dst[1] = make_float4(contrib[4], contrib[5], contrib[6], contrib[7]);
        dst[2] = make_float4(contrib[8], contrib[9], contrib[10], contrib[11]);
        dst[3] = make_float4(contrib[12], contrib[13], contrib[14], contrib[15]);
    }
    // zero slices 128..255
    *(float4*)&sp[(size_t)n * 4096 + 2048 + t * 4] = make_float4(0.f, 0.f, 0.f, 0.f);
}

// ---------------------------------------------------------------------------
// Per-step: reduce sp (coalesced [r][256][16] layout) + softmax -> w_ws,
// and pack x[:, ts] into the frag-linear xf buffer. 128 blocks x 64 threads.
// ---------------------------------------------------------------------------
__global__ __launch_bounds__(64) void k_soft(
    const float* __restrict__ spin, float* __restrict__ w_ws,
    const float* __restrict__ x, unsigned short* __restrict__ xf, int ts) {
    __shared__ float sq[16];
    const int n = blockIdx.x;
    const int lane = threadIdx.x;
    f32x4 acc = {0.f, 0.f, 0.f, 0.f};
    const float4* base = (const float4*)(spin + (size_t)n * 4096);
#pragma unroll
    for (int it = 0; it < 16; ++it) {
        const float4 v = base[it * 64 + lane];
        acc[0] += v.x; acc[1] += v.y; acc[2] += v.z; acc[3] += v.w;
    }
#pragma unroll
    for (int m = 4; m <= 32; m <<= 1) {
        acc[0] += __shfl_xor(acc[0], m);
        acc[1] += __shfl_xor(acc[1], m);
        acc[2] += __shfl_xor(acc[2], m);
        acc[3] += __shfl_xor(acc[3], m);
    }
    if (lane < 4) *(float4*)&sq[lane * 4] = make_float4(acc[0], acc[1], acc[2], acc[3]);
    __syncthreads();
    if (lane < 16) {
        const float s = sq[lane] * 0.03125f;
        float mx = s;
#pragma unroll
        for (int m = 1; m < 16; m <<= 1) mx = fmaxf(mx, __shfl_xor(mx, m));
        const float e = __expf(s - mx);
        float se = e;
#pragma unroll
        for (int m = 1; m < 16; m <<= 1) se += __shfl_xor(se, m);
        w_ws[n * 16 + lane] = e / se;
    }
    // pack x[:, ts]
    const float4* xp = (const float4*)&x[((size_t)n * 128 + ts) * 1024];
#pragma unroll
    for (int i = 0; i < 2; ++i) {
        const int js = lane * 2 + i;       // 0..127
        const float4 x0 = xp[js * 2], x1 = xp[js * 2 + 1];
        unsigned short v[8] = {f2bf(x0.x), f2bf(x0.y), f2bf(x0.z), f2bf(x0.w),
                               f2bf(x1.x), f2bf(x1.y), f2bf(x1.z), f2bf(x1.w)};
        const int j0 = js * 8;
        const int l = (n & 15) | (((j0 >> 3) & 3) << 4);
        *(int4*)&xf[(size_t)(((n >> 4) * 32 + (j0 >> 5)) * 64 + l) * 8] = *(const int4*)v;
    }
}

// ---------------------------------------------------------------------------
// One time step. 256 blocks x 512 threads. Block (cs = bid>>1, rh = bid&1):
// 64 rows x 32 reordered cols, K=2048 split over kh wave-halves.
// GEMM: explicitly software-pipelined (named register sets, 4-kc dbuf).
// Epilogue gathers (AW, cst, w_ws) hoisted before the barrier; epilogue
// split across BOTH wave-halves (cf = kh) via symmetric LDS acc exchange.
// ---------------------------------------------------------------------------
__global__ __launch_bounds__(512) void k_step(
    const unsigned short* __restrict__ WTf, const unsigned short* __restrict__ AW,
    const unsigned short* __restrict__ hFin, unsigned short* __restrict__ hFout,
    const unsigned short* __restrict__ xf,
    const float* __restrict__ w_ws, float* __restrict__ spout,
    float* __restrict__ cst, const float* __restrict__ Ag,
    const float* __restrict__ bias4, float* __restrict__ out, int ts) {
    __shared__ float wlds[64][17];       // 4.25 KB
    __shared__ float accred[2048];       // 8 KB
    const int bid = blockIdx.x;
    const int cs = bid >> 1, rh = bid & 1;
    const int tid = threadIdx.x;
    const int lane = tid & 63, wave = tid >> 6;
    const int rf = wave & 3, kh = wave >> 2;

    // ---- software-pipelined GEMM ----
    f32x4 acc0 = {0.f, 0.f, 0.f, 0.f}, acc1 = {0.f, 0.f, 0.f, 0.f};
    {
        const unsigned short* ap = (kh == 0 ? hFin : xf)
            + ((size_t)((rh * 4 + rf) * 32) * 64 + lane) * 8;
        const unsigned short* bp = WTf
            + ((size_t)((cs * 64 + kh * 32) * 2) * 64 + lane) * 8;
        bf16x8 ax[4], bx0[4], bx1[4], ay[4], by0[4], by1[4];
#pragma unroll
        for (int i = 0; i < 4; ++i) {
            ax[i]  = *(const bf16x8*)(ap + (size_t)i * 512);
            bx0[i] = *(const bf16x8*)(bp + (size_t)i * 1024);
            bx1[i] = *(const bf16x8*)(bp + (size_t)i * 1024 + 512);
        }
#pragma unroll
        for (int kb = 0; kb < 32; kb += 8) {
#pragma unroll
            for (int i = 0; i < 4; ++i) {
                const int kc = kb + 4 + i;
                ay[i]  = *(const bf16x8*)(ap + (size_t)kc * 512);
                by0[i] = *(const bf16x8*)(bp + (size_t)kc * 1024);
                by1[i] = *(const bf16x8*)(bp + (size_t)kc * 1024 + 512);
            }
#pragma unroll
            for (int i = 0; i < 4; ++i) {
                acc0 = __builtin_amdgcn_mfma_f32_16x16x32_bf16(ax[i], bx0[i], acc0, 0, 0, 0);
                acc1 = __builtin_amdgcn_mfma_f32_16x16x32_bf16(ax[i], bx1[i], acc1, 0, 0, 0);
            }
            if (kb + 8 < 32) {
#pragma unroll
                for (int i = 0; i < 4; ++i) {
                    const int kc = kb + 8 + i;
                    ax[i]  = *(const bf16x8*)(ap + (size_t)kc * 512);
                    bx0[i] = *(const bf16x8*)(bp + (size_t)kc * 1024);
                    bx1[i] = *(const bf16x8*)(bp + (size_t)kc * 1024 + 512);
                }
            }
#pragma unroll
            for (int i = 0; i < 4; ++i) {
                acc0 = __builtin_amdgcn_mfma_f32_16x16x32_bf16(ay[i], by0[i], acc0, 0, 0, 0);
                acc1 = __builtin_amdgcn_mfma_f32_16x16x32_bf16(ay[i], by1[i], acc1, 0, 0, 0);
            }
        }
    }

    // ---- hoisted epilogue gathers (latency hides under exchange) ----
    const int lq = lane & 15;
    const int hi = lane >> 4;
    const int mycol = cs * 32 + kh * 16 + lq;
    const int u = mycol >> 2, g = mycol & 3;
    int4 aw0[4], aw1[4];
    float cold[4];
#pragma unroll
    for (int reg = 0; reg < 4; ++reg) {
        const int r = rh * 64 + rf * 16 + hi * 4 + reg;
        const int4* awv = (const int4*)&AW[((size_t)r * 4096 + mycol) * 16];
        aw0[reg] = awv[0];
        aw1[reg] = awv[1];
        cold[reg] = cst[r * 1024 + u];
    }
    // stage softmax weights
#pragma unroll
    for (int it = 0; it < 2; ++it) {
        const int idx = it * 512 + tid;   // 1024 = 64 x 16
        wlds[idx >> 4][idx & 15] = w_ws[(rh * 64 + (idx >> 4)) * 16 + (idx & 15)];
    }
    // exchange other-cf accumulator
    const f32x4 accoth = (kh == 0) ? acc1 : acc0;
    *(f32x4*)&accred[((rf * 2 + kh) * 64 + lane) * 4] = accoth;
    __syncthreads();
    f32x4 acc = (kh == 0) ? acc0 : acc1;
    acc += *(const f32x4*)&accred[((rf * 2 + (kh ^ 1)) * 64 + lane) * 4];

    // ---- epilogue (both wave-halves; each handles its cf=kh 16 cols) ----
    const float bias = bias4[g * 1024 + u];
    float nhv[4];
#pragma unroll
    for (int reg = 0; reg < 4; ++reg) {
        const int r = rh * 64 + rf * 16 + hi * 4 + reg;
        const int rl = rf * 16 + hi * 4 + reg;
        union { int4 v; unsigned short us[8]; } a0u, a1u;
        a0u.v = aw0[reg]; a1u.v = aw1[reg];
        float aextra = 0.f;
#pragma unroll
        for (int p = 0; p < 8; ++p) aextra += wlds[rl][p] * bf2f(a0u.us[p]);
#pragma unroll
        for (int p = 0; p < 8; ++p) aextra += wlds[rl][8 + p] * bf2f(a1u.us[p]);
        float a = acc[reg] + bias + aextra;
        float v1 = __shfl_xor(a, 1);
        float v2 = __shfl_xor(a, 2);
        float v3 = __shfl_xor(a, 3);
        auto pick = [&](int m) { return m == 0 ? a : m == 1 ? v1 : m == 2 ? v2 : v3; };
        float ii = sigf(pick(g));
        float ff = sigf(pick(g ^ 1));
        float oo = sigf(pick(g ^ 2));
        float gg = tanhf_fast(pick(g ^ 3));
        const float nc = ff * cold[reg] + ii * gg;
        const float nh = oo * tanhf_fast(nc);
        nhv[reg] = nh;
        if (g == 0) {
            cst[r * 1024 + u] = nc;
        } else if (g == 1) {
            hFout[(size_t)(((r >> 4) * 32 + (u >> 5)) * 64 +
                           ((r & 15) | (((u >> 3) & 3) << 4))) * 8 + (u & 7)] = f2bf(nh);
        } else if (g == 3) {
            out[((size_t)r * 128 + ts) * 1024 + u] = nh;
        }
    }
    // ---- next-step score partials (gate-2 lanes; slice = cs*2 + kh) ----
    if ((lq & 3) == 2) {
#pragma unroll
        for (int reg = 0; reg < 4; ++reg) {
            const int r = rh * 64 + rf * 16 + hi * 4 + reg;
            const float nh = nhv[reg];
            const float4* Ap = (const float4*)&Ag[((size_t)r * 1024 + u) * 16];
            float contrib[16];
#pragma unroll
            for (int q = 0; q < 4; ++q) {
                const float4 cv = Ap[q];
                contrib[q * 4 + 0] = nh * cv.x;
                contrib[q * 4 + 1] = nh * cv.y;
                contrib[q * 4 + 2] = nh * cv.z;
                contrib[q * 4 + 3] = nh * cv.w;
            }
#pragma unroll
            for (int p = 0; p < 16; ++p) {
                contrib[p] += __shfl_xor(contrib[p], 4);
                contrib[p] += __shfl_xor(contrib[p], 8);
            }
            if (lq == 2) {
                float4* dst = (float4*)&spout[((size_t)r * 256 + (cs * 2 + kh)) * 16];
                dst[0] = make_float4(contrib[0], contrib[1], contrib[2], contrib[3]);
                dst[1] = make_float4(contrib[4], contrib[5], contrib[6], contrib[7]);
                dst[2] = make_float4(contrib[8], contrib[9], contrib[10], contrib[11]);
                dst[3] = make_float4(contrib[12], contrib[13], contrib[14], contrib[15]);
            }
        }
    }
}

extern "C" void kernel_launch(void* const* d_in, const int* in_sizes, int n_in,
                              void* d_out, int out_size, void* d_ws, size_t ws_size,
                              hipStream_t stream) {
    const float* x     = (const float*)d_in[0];   // (128,128,1024)
    const float* A     = (const float*)d_in[1];   // (128,1024,4,4)
    const float* Wx    = (const float*)d_in[2];   // (1024,4096)
    const float* Wh    = (const float*)d_in[3];   // (1024,4096)
    const float* Wattn = (const float*)d_in[4];   // (1024,4096)
    const float* b     = (const float*)d_in[5];   // (4096,)
    float* out = (float*)d_out;                   // (128,128,1024) f32

    char* ws = (char*)d_ws;
    unsigned short* WTf = (unsigned short*)(ws);                // 16 MB
    unsigned short* AW  = (unsigned short*)(ws + 16777216);     // 16 MB
    unsigned short* hF0 = (unsigned short*)(ws + 33554432);     // 256 KB
    unsigned short* hF1 = (unsigned short*)(ws + 33816576);     // 256 KB
    unsigned short* xf  = (unsigned short*)(ws + 34078720);     // 256 KB
    float* cst  = (float*)(ws + 34340864);                      // 512 KB
    float* w_ws = (float*)(ws + 34865152);                      // 8 KB
    float* sp0  = (float*)(ws + 34873344);                      // 2 MB
    float* sp1  = (float*)(ws + 36970496);                      // 2 MB -> 39067648
    // transient build buffers (used strictly before k_init in stream order):
    unsigned short* ATf = (unsigned short*)(ws + 33554432);     // 4 MB
    unsigned short* WAf = (unsigned short*)(ws + 37748736);     // 8 MB -> 46137344

    k_build_wtf2<<<dim3(64, 32), 256, 0, stream>>>(Wh, Wx, WTf);
    if (ws_size >= 46137344u) {
        k_build_waf<<<dim3(64, 16), 256, 0, stream>>>(Wattn, WAf);
        k_pack_at<<<128, 256, 0, stream>>>(A, ATf);
        k_aw_gemm<<<dim3(16, 32), 512, 0, stream>>>(ATf, WAf, AW);
    } else {
        k_build_aw<<<dim3(32, 8), 512, 65536, stream>>>(Wattn, A, AW);
    }
    k_init<<<128, 512, 0, stream>>>(A, cst, hF0, sp0);

    for (int ts = 0; ts < 128; ++ts) {
        unsigned short* hin  = (ts & 1) ? hF1 : hF0;
        unsigned short* hout = (ts & 1) ? hF0 : hF1;
        float* spin  = (ts & 1) ? sp1 : sp0;
        float* spout = (ts & 1) ? sp0 : sp1;
        k_soft<<<128, 64, 0, stream>>>(spin, w_ws, x, xf, ts);
        k_step<<<256, 512, 0, stream>>>(WTf, AW, hin, hout, xf,
                                        w_ws, spout, cst, A, b, out, ts);
    }
}